// Round 1
// 681.909 us; speedup vs baseline: 1.1028x; 1.1028x over previous
//
#include <hip/hip_runtime.h>
#include <hip/hip_bf16.h>

#define BATCH 8
#define CH 256
#define SPAT 16384
#define TP 64       // pixel tile
#define PITCH 272   // LDS channel pitch in halfwords: 544B rows, 16B-aligned, mult of 8

typedef __attribute__((ext_vector_type(4))) float f32x4;
typedef __attribute__((ext_vector_type(8))) __bf16 bf16x8;
typedef __attribute__((ext_vector_type(4))) __bf16 bf16x4;

// workspace float offsets
#define WS_ROWSUM  512      // 2048  (zeroed)
#define WS_POOLED  2560     // 16
#define WS_BKF     2576     // 256 folded biases
#define WS_BQF     2832
#define WS_BVF     3088
#define WS_SUM     3344     // 256 (zeroed)
#define WS_SSUM    3600     // 256 (zeroed)
#define WS_CTX     4096     // 16*128*128 = 262144 (zeroed)
#define WS_MBF     266240   // 8*256*256 bf16 = 262144 floats
#define WS_WKBF    528384   // 65536 bf16 = 32768 floats
#define WS_WQBF    561152
#define WS_WVBF    593920

// bijective LDS swizzle on halfword index: XOR bits 3-5 with bits 7-9.
// All vector accesses are <=8 halfwords from a base with matching low bits,
// so the swizzle field (bits>=7) is constant across each vector access.
__device__ __forceinline__ int lswz(int h) { return h ^ (((h >> 7) & 7) << 3); }

__device__ __forceinline__ void blockReduce2(float& a, float& b, volatile float* sm) {
    int lane = threadIdx.x & 63, w = threadIdx.x >> 6;
#pragma unroll
    for (int o = 32; o; o >>= 1) { a += __shfl_down(a, o); b += __shfl_down(b, o); }
    if (lane == 0) { sm[w] = a; sm[4 + w] = b; }
    __syncthreads();
    if (threadIdx.x == 0) {
        a = sm[0] + sm[1] + sm[2] + sm[3];
        b = sm[4] + sm[5] + sm[6] + sm[7];
    }
}

// ---- BN batch stats: per-(b,c) partial sums, atomically accumulated ----
__global__ __launch_bounds__(256) void ea_bnstats(const float* __restrict__ x,
                                                  float* sums, float* ssums) {
    __shared__ float sm[8];
    int bi = blockIdx.x, c = bi >> 3, b = bi & 7;
    const float4* p = (const float4*)(x + (size_t)(b * CH + c) * SPAT);
    float sum = 0.f, ss = 0.f;
    for (int i = threadIdx.x; i < SPAT / 4; i += 256) {
        float4 v = p[i];
        sum += v.x + v.y + v.z + v.w;
        ss  += v.x * v.x + v.y * v.y + v.z * v.z + v.w * v.w;
    }
    blockReduce2(sum, ss, sm);
    if (threadIdx.x == 0) { atomicAdd(sums + c, sum); atomicAdd(ssums + c, ss); }
}

// ---- fold BN scale/shift into bf16 weights + fp32 biases ----
// wX'[o][c] = wX[o][c]*scale[c];  bX'[o] = bX[o] + sum_c wX[o][c]*shift[c]
__global__ __launch_bounds__(256) void ea_fold(const float* __restrict__ wk, const float* __restrict__ wq,
        const float* __restrict__ wv, const float* __restrict__ bk, const float* __restrict__ bq,
        const float* __restrict__ bv, const float* __restrict__ gamma, const float* __restrict__ beta,
        const float* __restrict__ sums, const float* __restrict__ ssums,
        __bf16* wkb, __bf16* wqb, __bf16* wvb, float* bkf, float* bqf, float* bvf) {
    __shared__ float sm[12];
    int o = blockIdx.x, c = threadIdx.x;
    const float inv = 1.f / (float)(BATCH * SPAT);
    float mean = sums[c] * inv;
    float var  = ssums[c] * inv - mean * mean;
    float sc   = gamma[c] * rsqrtf(var + 1e-5f);
    float sh   = beta[c] - mean * sc;
    float k = wk[o * 256 + c], q = wq[o * 256 + c], v = wv[o * 256 + c];
    wkb[o * 256 + c] = (__bf16)(k * sc);
    wqb[o * 256 + c] = (__bf16)(q * sc);
    wvb[o * 256 + c] = (__bf16)(v * sc);
    float ak = k * sh, aq = q * sh, av = v * sh;
    int lane = c & 63, w = c >> 6;
#pragma unroll
    for (int off = 32; off; off >>= 1) {
        ak += __shfl_down(ak, off);
        aq += __shfl_down(aq, off);
        av += __shfl_down(av, off);
    }
    if (lane == 0) { sm[w] = ak; sm[4 + w] = aq; sm[8 + w] = av; }
    __syncthreads();
    if (c == 0) {
        bkf[o] = bk[o] + sm[0] + sm[1] + sm[2] + sm[3];
        bqf[o] = bq[o] + sm[4] + sm[5] + sm[6] + sm[7];
        bvf[o] = bv[o] + sm[8] + sm[9] + sm[10] + sm[11];
    }
}

// stage raw x tile into LDS as swizzled [px][ch] bf16 (BN pre-folded into weights).
// float4 loads along px: 16 loads/thread instead of 64 scalars.
__device__ __forceinline__ void stage_x(const float* xb, __bf16* Xl, int t) {
    int l15 = t & 15, c0 = t >> 4;
    const float* xp = xb + l15 * 4;
    int hbase = (l15 * 4) * PITCH;
#pragma unroll
    for (int i = 0; i < 16; i++) {
        int c = c0 * 16 + i;
        float4 v = *(const float4*)(xp + (size_t)c * SPAT);
        Xl[lswz(hbase + c)]             = (__bf16)v.x;
        Xl[lswz(hbase + PITCH + c)]     = (__bf16)v.y;
        Xl[lswz(hbase + 2 * PITCH + c)] = (__bf16)v.z;
        Xl[lswz(hbase + 3 * PITCH + c)] = (__bf16)v.w;
    }
}

// per-wave 64x64 strip of a [256 x 64px] GEMM, K=256. A global bf16 (row stride 256),
// B in swizzled LDS [px][ch]. Output column l15 of tile nt corresponds to px = 4*l15+nt,
// so each lane owns 4 CONSECUTIVE pixels per row -> vector stores in the epilogues.
__device__ __forceinline__ void mm256(const __bf16* __restrict__ A, const __bf16* Xl,
                                      int WB, int quad, int l15, f32x4 (&acc)[4][4]) {
#pragma unroll 2
    for (int ks = 0; ks < 8; ks++) {
        int k0 = ks * 32;
        bf16x8 a[4];
#pragma unroll
        for (int mt = 0; mt < 4; mt++)
            a[mt] = *(const bf16x8*)(A + (WB + mt * 16 + l15) * 256 + k0 + quad * 8);
        bf16x8 bb[4];
#pragma unroll
        for (int nt = 0; nt < 4; nt++)
            bb[nt] = *(const bf16x8*)(Xl + lswz((4 * l15 + nt) * PITCH + k0 + quad * 8));
#pragma unroll
        for (int mt = 0; mt < 4; mt++)
#pragma unroll
            for (int nt = 0; nt < 4; nt++)
                acc[mt][nt] = __builtin_amdgcn_mfma_f32_16x16x32_bf16(a[mt], bb[nt], acc[mt][nt], 0, 0, 0);
    }
}

// ---- fused: K/V projection on folded weights; writes p=exp(k) and v as bf16 (vectorized); rowsums ----
__global__ __launch_bounds__(256) void ea_projkv(const float* __restrict__ x,
        const __bf16* __restrict__ wkb, const __bf16* __restrict__ wvb,
        const float* __restrict__ bkf, const float* __restrict__ bvf,
        __bf16* __restrict__ pbuf, __bf16* __restrict__ vbuf, float* __restrict__ rowsum) {
    __shared__ __bf16 X[TP * PITCH];
    int bi = blockIdx.x, b = bi >> 8, s0 = (bi & 255) * TP, t = threadIdx.x;
    stage_x(x + (size_t)b * CH * SPAT + s0, X, t);
    __syncthreads();

    int lane = t & 63, wave = t >> 6, quad = lane >> 4, l15 = lane & 15, WB = wave * 64;
    const f32x4 z = {0.f, 0.f, 0.f, 0.f};

    // K projection -> p = exp(k)
    {
        f32x4 acc[4][4];
#pragma unroll
        for (int mt = 0; mt < 4; mt++)
#pragma unroll
            for (int nt = 0; nt < 4; nt++) acc[mt][nt] = z;
        mm256(wkb, X, WB, quad, l15, acc);
#pragma unroll
        for (int mt = 0; mt < 4; mt++) {
            int row0 = WB + mt * 16 + quad * 4;
#pragma unroll
            for (int r = 0; r < 4; r++) {
                int row = row0 + r;
                float bs = bkf[row];
                float e0 = __expf(acc[mt][0][r] + bs);
                float e1 = __expf(acc[mt][1][r] + bs);
                float e2 = __expf(acc[mt][2][r] + bs);
                float e3 = __expf(acc[mt][3][r] + bs);
                bf16x4 pk = {(__bf16)e0, (__bf16)e1, (__bf16)e2, (__bf16)e3};
                *(bf16x4*)(pbuf + (size_t)(b * CH + row) * SPAT + s0 + 4 * l15) = pk;
                float rs = e0 + e1 + e2 + e3;
#pragma unroll
                for (int o = 1; o < 16; o <<= 1) rs += __shfl_xor(rs, o);
                if (l15 == 0) atomicAdd(rowsum + b * CH + row, rs);
            }
        }
    }
    // V projection
    {
        f32x4 acc[4][4];
#pragma unroll
        for (int mt = 0; mt < 4; mt++)
#pragma unroll
            for (int nt = 0; nt < 4; nt++) acc[mt][nt] = z;
        mm256(wvb, X, WB, quad, l15, acc);
#pragma unroll
        for (int mt = 0; mt < 4; mt++) {
            int row0 = WB + mt * 16 + quad * 4;
#pragma unroll
            for (int r = 0; r < 4; r++) {
                int row = row0 + r;
                float bs = bvf[row];
                bf16x4 vk = {(__bf16)(acc[mt][0][r] + bs), (__bf16)(acc[mt][1][r] + bs),
                             (__bf16)(acc[mt][2][r] + bs), (__bf16)(acc[mt][3][r] + bs)};
                *(bf16x4*)(vbuf + (size_t)(b * CH + row) * SPAT + s0 + 4 * l15) = vk;
            }
        }
    }
}

// ---- context: ctx[b,h] += p_chunk @ v_chunk^T (unnormalized) ---- (unchanged)
__global__ __launch_bounds__(256) void ea_context(const __bf16* pbuf, const __bf16* vbuf, float* ctx) {
    int bi = blockIdx.x, b = bi >> 5, h = (bi >> 4) & 1, chunk = bi & 15;
    int sb = chunk * 1024;
    int t = threadIdx.x, lane = t & 63, wave = t >> 6, quad = lane >> 4, l15 = lane & 15;
    int WB = wave * 32;
    const __bf16* pb = pbuf + (size_t)(b * CH + h * 128) * SPAT;
    const __bf16* vb = vbuf + (size_t)(b * CH + h * 128) * SPAT;
    const f32x4 z = {0.f, 0.f, 0.f, 0.f};
    f32x4 acc[2][8];
#pragma unroll
    for (int mt = 0; mt < 2; mt++)
#pragma unroll
        for (int nt = 0; nt < 8; nt++) acc[mt][nt] = z;

#pragma unroll 2
    for (int ks = 0; ks < 32; ks++) {
        int k0 = sb + ks * 32;
        bf16x8 a[2];
#pragma unroll
        for (int mt = 0; mt < 2; mt++)
            a[mt] = *(const bf16x8*)(pb + (size_t)(WB + mt * 16 + l15) * SPAT + k0 + quad * 8);
        bf16x8 bb[8];
#pragma unroll
        for (int nt = 0; nt < 8; nt++)
            bb[nt] = *(const bf16x8*)(vb + (size_t)(nt * 16 + l15) * SPAT + k0 + quad * 8);
#pragma unroll
        for (int mt = 0; mt < 2; mt++)
#pragma unroll
            for (int nt = 0; nt < 8; nt++)
                acc[mt][nt] = __builtin_amdgcn_mfma_f32_16x16x32_bf16(a[mt], bb[nt], acc[mt][nt], 0, 0, 0);
    }
    float* cbase = ctx + (size_t)(b * 2 + h) * 16384;
#pragma unroll
    for (int mt = 0; mt < 2; mt++)
#pragma unroll
        for (int nt = 0; nt < 8; nt++)
#pragma unroll
            for (int r = 0; r < 4; r++) {
                int kk = WB + mt * 16 + quad * 4 + r, vv = nt * 16 + l15;
                atomicAdd(cbase + kk * 128 + vv, acc[mt][nt][r]);
            }
}

// ---- normalize ctx rows by rowsum, compute pooled mean ---- (unchanged)
__global__ void ea_normpool(float* ctx, const float* rowsum, float* pooled) {
    __shared__ float sm[8];
    int bi = blockIdx.x, b = bi >> 1, h = bi & 1;
    float* base = ctx + (size_t)bi * 16384;
    const float* rs = rowsum + b * CH + h * 128;
    float sum = 0.f, dummy = 0.f;
    for (int i = threadIdx.x; i < 16384; i += 256) {
        float v = base[i] / rs[i >> 7];
        base[i] = v;
        sum += v;
    }
    blockReduce2(sum, dummy, sm);
    if (threadIdx.x == 0) pooled[bi] = sum * (1.f / 16384.f);
}

// ---- SE gate + fold w_rep ---- (unchanged)
__global__ __launch_bounds__(256) void ea_M(const float* ctx, const float* pooled,
                                            const float* wfc1, const float* bfc1,
                                            const float* wfc2, const float* bfc2,
                                            const float* wse, const float* bse,
                                            const float* wrep, __bf16* Mbf) {
    __shared__ float L[128 * 128];
    int bi = blockIdx.x, b = bi >> 3, h = (bi >> 2) & 1, strip = bi & 3;
    float p0 = pooled[b * 2], p1 = pooled[b * 2 + 1];
    float z10 = fmaxf(0.f, wfc1[0] * p0 + wfc1[1] * p1 + bfc1[0]);
    float z11 = fmaxf(0.f, wfc1[2] * p0 + wfc1[3] * p1 + bfc1[1]);
    float z20 = wfc2[0] * z10 + wfc2[1] * z11 + bfc2[0];
    float z21 = wfc2[2] * z10 + wfc2[3] * z11 + bfc2[1];
    float g0 = 1.f / (1.f + __expf(-z20)), g1 = 1.f / (1.f + __expf(-z21));
    float a0 = wse[0] * g0, a1 = wse[1] * g1, bs = bse[0];
    const float* c0 = ctx + (size_t)b * 2 * 16384;
    const float* c1 = c0 + 16384;
    for (int i = threadIdx.x; i < 16384; i += 256) L[i] = a0 * c0[i] + a1 * c1[i] + bs;
    __syncthreads();
    int o = strip * 64 + (threadIdx.x & 63), kb = (threadIdx.x >> 6) * 32;
    const float4* wr = (const float4*)(wrep + (size_t)o * 256 + h * 128);
    for (int kk = kb; kk < kb + 32; kk++) {
        const float4* Lr = (const float4*)(L + kk * 128);
        float acc = 0.f;
#pragma unroll 8
        for (int j = 0; j < 32; j++) {
            float4 w4 = wr[j];
            float4 l4 = Lr[j];
            acc += w4.x * l4.x + w4.y * l4.y + w4.z * l4.z + w4.w * l4.w;
        }
        Mbf[(size_t)(b * 256 + o) * 256 + h * 128 + kk] = (__bf16)acc;
    }
}

// ---- final: q = wq'@x+bq', channel-softmax per head, out = M@qsoft + b_rep ----
__global__ __launch_bounds__(256) void ea_final(const float* __restrict__ x,
        const __bf16* __restrict__ wqb, const float* __restrict__ bqf,
        const __bf16* __restrict__ Mbf, const float* __restrict__ brep, float* __restrict__ out) {
    __shared__ __bf16 X[TP * PITCH];
    __shared__ __bf16 Q[TP * PITCH];
    __shared__ float psum[256];
    __shared__ float rcp[TP * 2];
    int bi = blockIdx.x, b = bi >> 8, s0 = (bi & 255) * TP, t = threadIdx.x;
    stage_x(x + (size_t)b * CH * SPAT + s0, X, t);
    __syncthreads();

    int lane = t & 63, wave = t >> 6, quad = lane >> 4, l15 = lane & 15, WB = wave * 64;
    const f32x4 z = {0.f, 0.f, 0.f, 0.f};

    // matmul1: q-logits -> exp -> Q[px][ch] (bf16x4 LDS writes: 4 consecutive channels)
    {
        f32x4 acc[4][4];
#pragma unroll
        for (int mt = 0; mt < 4; mt++)
#pragma unroll
            for (int nt = 0; nt < 4; nt++) acc[mt][nt] = z;
        mm256(wqb, X, WB, quad, l15, acc);
#pragma unroll
        for (int mt = 0; mt < 4; mt++) {
            int row0 = WB + mt * 16 + quad * 4;
#pragma unroll
            for (int nt = 0; nt < 4; nt++) {
                bf16x4 qk;
#pragma unroll
                for (int r = 0; r < 4; r++)
                    qk[r] = (__bf16)__expf(acc[mt][nt][r] + bqf[row0 + r]);
                *(bf16x4*)(Q + lswz((4 * l15 + nt) * PITCH + row0)) = qk;
            }
        }
    }
    __syncthreads();
    // column sums per (px, head): vectorized bf16x8 LDS reads
    {
        int px = t & 63, hh = (t >> 6) & 1, part = t >> 7;
        int cb = hh * 128 + part * 64;
        float s = 0.f;
#pragma unroll
        for (int j = 0; j < 8; j++) {
            bf16x8 qv = *(const bf16x8*)(Q + lswz(px * PITCH + cb + j * 8));
#pragma unroll
            for (int e = 0; e < 8; e++) s += (float)qv[e];
        }
        psum[t] = s;
    }
    __syncthreads();
    if (t < 128) {
        float tot = psum[t] + psum[t + 128];
        rcp[(t & 63) * 2 + (t >> 6)] = 1.f / tot;
    }
    __syncthreads();
    // normalize Q in place (bf16x8 RMW)
#pragma unroll 2
    for (int e = t; e < TP * 32; e += 256) {
        int px = e >> 5, cc = (e & 31) * 8;
        float sc = rcp[px * 2 + (cc >> 7)];
        int h = lswz(px * PITCH + cc);
        bf16x8 qv = *(const bf16x8*)(Q + h);
        bf16x8 qo;
#pragma unroll
        for (int j2 = 0; j2 < 8; j2++) qo[j2] = (__bf16)((float)qv[j2] * sc);
        *(bf16x8*)(Q + h) = qo;
    }
    __syncthreads();
    // matmul2: out = M @ qsoft + b_rep (float4 stores: 4 consecutive px per lane)
    {
        f32x4 acc[4][4];
#pragma unroll
        for (int mt = 0; mt < 4; mt++)
#pragma unroll
            for (int nt = 0; nt < 4; nt++) acc[mt][nt] = z;
        mm256(Mbf + (size_t)b * 65536, Q, WB, quad, l15, acc);
#pragma unroll
        for (int mt = 0; mt < 4; mt++) {
            int row0 = WB + mt * 16 + quad * 4;
#pragma unroll
            for (int r = 0; r < 4; r++) {
                int row = row0 + r;
                float bs = brep[row];
                f32x4 o4 = {acc[mt][0][r] + bs, acc[mt][1][r] + bs,
                            acc[mt][2][r] + bs, acc[mt][3][r] + bs};
                *(f32x4*)(out + (size_t)(b * CH + row) * SPAT + s0 + 4 * l15) = o4;
            }
        }
    }
}

extern "C" void kernel_launch(void* const* d_in, const int* in_sizes, int n_in,
                              void* d_out, int out_size, void* d_ws, size_t ws_size,
                              hipStream_t stream) {
    (void)in_sizes; (void)n_in; (void)out_size; (void)ws_size;
    const float* x     = (const float*)d_in[0];
    const float* gamma = (const float*)d_in[1];
    const float* beta  = (const float*)d_in[2];
    const float* wk    = (const float*)d_in[3];
    const float* bk    = (const float*)d_in[4];
    const float* wq    = (const float*)d_in[5];
    const float* bq    = (const float*)d_in[6];
    const float* wv    = (const float*)d_in[7];
    const float* bv    = (const float*)d_in[8];
    const float* wfc1  = (const float*)d_in[9];
    const float* bfc1  = (const float*)d_in[10];
    const float* wfc2  = (const float*)d_in[11];
    const float* bfc2  = (const float*)d_in[12];
    const float* wse   = (const float*)d_in[13];
    const float* bse   = (const float*)d_in[14];
    const float* wrep  = (const float*)d_in[15];
    const float* brep  = (const float*)d_in[16];

    float* ws = (float*)d_ws;
    __bf16* wkb = (__bf16*)(ws + WS_WKBF);
    __bf16* wqb = (__bf16*)(ws + WS_WQBF);
    __bf16* wvb = (__bf16*)(ws + WS_WVBF);
    __bf16* Mbf = (__bf16*)(ws + WS_MBF);

    // p and v staged as bf16 inside d_out (exactly fills 134 MB); final kernel overwrites with fp32 out
    __bf16* pbuf = (__bf16*)d_out;
    __bf16* vbuf = pbuf + (size_t)BATCH * CH * SPAT;
    float* out = (float*)d_out;

    hipMemsetAsync((void*)(ws + WS_ROWSUM), 0,
                   (size_t)(WS_MBF - WS_ROWSUM) * sizeof(float), stream);
    ea_bnstats<<<2048, 256, 0, stream>>>(x, ws + WS_SUM, ws + WS_SSUM);
    ea_fold<<<256, 256, 0, stream>>>(wk, wq, wv, bk, bq, bv, gamma, beta,
                                     ws + WS_SUM, ws + WS_SSUM,
                                     wkb, wqb, wvb, ws + WS_BKF, ws + WS_BQF, ws + WS_BVF);
    ea_projkv<<<2048, 256, 0, stream>>>(x, wkb, wvb, ws + WS_BKF, ws + WS_BVF,
                                        pbuf, vbuf, ws + WS_ROWSUM);
    ea_context<<<256, 256, 0, stream>>>(pbuf, vbuf, ws + WS_CTX);
    ea_normpool<<<16, 256, 0, stream>>>(ws + WS_CTX, ws + WS_ROWSUM, ws + WS_POOLED);
    ea_M<<<64, 256, 0, stream>>>(ws + WS_CTX, ws + WS_POOLED, wfc1, bfc1, wfc2, bfc2,
                                 wse, bse, wrep, Mbf);
    ea_final<<<2048, 256, 0, stream>>>(x, wqb, ws + WS_BQF, Mbf, brep, out);
}

// Round 2
// 604.929 us; speedup vs baseline: 1.2431x; 1.1273x over previous
//
#include <hip/hip_runtime.h>
#include <hip/hip_bf16.h>

#define BATCH 8
#define CH 256
#define SPAT 16384
#define TP 64       // pixel tile
#define PITCH 272   // (ea_final only) LDS channel pitch in halfwords

typedef __attribute__((ext_vector_type(4))) float f32x4;
typedef __attribute__((ext_vector_type(8))) __bf16 bf16x8;
typedef __attribute__((ext_vector_type(4))) __bf16 bf16x4;

// workspace float offsets
#define WS_ROWSUM  512      // 2048  (zeroed)
#define WS_POOLED  2560     // 16
#define WS_BKF     2576     // 256 folded biases
#define WS_BQF     2832
#define WS_BVF     3088
#define WS_SUM     3344     // 256 (zeroed)
#define WS_SSUM    3600     // 256 (zeroed)
#define WS_CTX     4096     // 16*128*128 = 262144 (zeroed)
#define WS_MBF     266240   // 8*256*256 bf16 = 262144 floats
#define WS_WKBF    528384   // 65536 bf16 = 32768 floats
#define WS_WQBF    561152
#define WS_WVBF    593920

// (ea_final only) bijective LDS swizzle on halfword index
__device__ __forceinline__ int lswz(int h) { return h ^ (((h >> 7) & 7) << 3); }

__device__ __forceinline__ void blockReduce2(float& a, float& b, volatile float* sm) {
    int lane = threadIdx.x & 63, w = threadIdx.x >> 6;
#pragma unroll
    for (int o = 32; o; o >>= 1) { a += __shfl_down(a, o); b += __shfl_down(b, o); }
    if (lane == 0) { sm[w] = a; sm[4 + w] = b; }
    __syncthreads();
    if (threadIdx.x == 0) {
        a = sm[0] + sm[1] + sm[2] + sm[3];
        b = sm[4] + sm[5] + sm[6] + sm[7];
    }
}

// ---- BN batch stats: per-(b,c) partial sums, atomically accumulated ----
__global__ __launch_bounds__(256) void ea_bnstats(const float* __restrict__ x,
                                                  float* sums, float* ssums) {
    __shared__ float sm[8];
    int bi = blockIdx.x, c = bi >> 3, b = bi & 7;
    const float4* p = (const float4*)(x + (size_t)(b * CH + c) * SPAT);
    float sum = 0.f, ss = 0.f;
    for (int i = threadIdx.x; i < SPAT / 4; i += 256) {
        float4 v = p[i];
        sum += v.x + v.y + v.z + v.w;
        ss  += v.x * v.x + v.y * v.y + v.z * v.z + v.w * v.w;
    }
    blockReduce2(sum, ss, sm);
    if (threadIdx.x == 0) { atomicAdd(sums + c, sum); atomicAdd(ssums + c, ss); }
}

// ---- fold BN scale/shift into bf16 weights + fp32 biases ----
__global__ __launch_bounds__(256) void ea_fold(const float* __restrict__ wk, const float* __restrict__ wq,
        const float* __restrict__ wv, const float* __restrict__ bk, const float* __restrict__ bq,
        const float* __restrict__ bv, const float* __restrict__ gamma, const float* __restrict__ beta,
        const float* __restrict__ sums, const float* __restrict__ ssums,
        __bf16* wkb, __bf16* wqb, __bf16* wvb, float* bkf, float* bqf, float* bvf) {
    __shared__ float sm[12];
    int o = blockIdx.x, c = threadIdx.x;
    const float inv = 1.f / (float)(BATCH * SPAT);
    float mean = sums[c] * inv;
    float var  = ssums[c] * inv - mean * mean;
    float sc   = gamma[c] * rsqrtf(var + 1e-5f);
    float sh   = beta[c] - mean * sc;
    float k = wk[o * 256 + c], q = wq[o * 256 + c], v = wv[o * 256 + c];
    wkb[o * 256 + c] = (__bf16)(k * sc);
    wqb[o * 256 + c] = (__bf16)(q * sc);
    wvb[o * 256 + c] = (__bf16)(v * sc);
    float ak = k * sh, aq = q * sh, av = v * sh;
    int lane = c & 63, w = c >> 6;
#pragma unroll
    for (int off = 32; off; off >>= 1) {
        ak += __shfl_down(ak, off);
        aq += __shfl_down(aq, off);
        av += __shfl_down(av, off);
    }
    if (lane == 0) { sm[w] = ak; sm[4 + w] = aq; sm[8 + w] = av; }
    __syncthreads();
    if (c == 0) {
        bkf[o] = bk[o] + sm[0] + sm[1] + sm[2] + sm[3];
        bqf[o] = bq[o] + sm[4] + sm[5] + sm[6] + sm[7];
        bvf[o] = bv[o] + sm[8] + sm[9] + sm[10] + sm[11];
    }
}

// ---- fused K/V projection + context accumulation ----
// 256 blocks = (batch b, 512-px chunk); 512 threads = 8 waves; 8 tiles of 64 px.
// X LDS layout:  addr = px*256 + (c ^ ((px>>2 & 7)<<3))   [swizzle varies per lane]
// P/V LDS layout: addr = row*64 + (px ^ ((row & 7)<<3))   [row-stride-128B conflict fix]
__global__ __launch_bounds__(512, 2) void ea_kvctx(const float* __restrict__ x,
        const __bf16* __restrict__ wkb, const __bf16* __restrict__ wvb,
        const float* __restrict__ bkf, const float* __restrict__ bvf,
        float* __restrict__ ctx, float* __restrict__ rowsum) {
    __shared__ __bf16 Xl[2 * 64 * 256];   // 64 KB double-buffered x tile
    __shared__ __bf16 Pl[256 * 64];       // 32 KB p = exp(k) tile
    __shared__ __bf16 Vl[256 * 64];       // 32 KB v tile
    const int bi = blockIdx.x, b = bi >> 5, chunk = bi & 31;
    const int t = threadIdx.x;
    const int lane = t & 63, wave = t >> 6, quad = lane >> 4, l15 = lane & 15;
    const int rbase = wave * 32;              // proj output rows for this wave
    const int sl = t & 15, cg = t >> 4;       // staging: px0 = 4*sl, c = cg*8 + i
    const int xswz = (sl & 7) << 3;
    const float* xp0 = x + (size_t)(b * CH + cg * 8) * SPAT + chunk * 512 + 4 * sl;

    float bkr[2][4], bvr[2][4];
#pragma unroll
    for (int mt = 0; mt < 2; mt++)
#pragma unroll
        for (int r = 0; r < 4; r++) {
            int row = rbase + mt * 16 + quad * 4 + r;
            bkr[mt][r] = bkf[row];
            bvr[mt][r] = bvf[row];
        }

    const f32x4 z = {0.f, 0.f, 0.f, 0.f};
    f32x4 cacc[4][4];
#pragma unroll
    for (int mt = 0; mt < 4; mt++)
#pragma unroll
        for (int nt = 0; nt < 4; nt++) cacc[mt][nt] = z;
    float rs_acc[2][4] = {{0.f, 0.f, 0.f, 0.f}, {0.f, 0.f, 0.f, 0.f}};

    const int head = wave >> 2, rh = (wave >> 1) & 1, chh = wave & 1;
    const int prow0 = head * 128 + rh * 64, vrow0 = head * 128 + chh * 64;

    // prologue: stage tile 0
    f32x4 xr[8];
#pragma unroll
    for (int i = 0; i < 8; i++) xr[i] = *(const f32x4*)(xp0 + (size_t)i * SPAT);
#pragma unroll
    for (int i = 0; i < 8; i++) {
        int ca = (cg * 8 + i) ^ xswz;
#pragma unroll
        for (int j = 0; j < 4; j++)
            Xl[(4 * sl + j) * 256 + ca] = (__bf16)xr[i][j];
    }
    __syncthreads();

    int buf = 0;
    for (int tt = 0; tt < 8; tt++) {
        // issue next tile's global loads early (latency hides under MFMAs)
        if (tt < 7) {
            const float* xp = xp0 + (tt + 1) * 64;
#pragma unroll
            for (int i = 0; i < 8; i++) xr[i] = *(const f32x4*)(xp + (size_t)i * SPAT);
        }
        // fused K+V projection: 32 rows x 64 px, K=256; B-frags shared between K and V
        const __bf16* Xb = Xl + buf * (64 * 256);
        f32x4 ak[2][4], av[2][4];
#pragma unroll
        for (int mt = 0; mt < 2; mt++)
#pragma unroll
            for (int nt = 0; nt < 4; nt++) { ak[mt][nt] = z; av[mt][nt] = z; }
#pragma unroll 1
        for (int ks = 0; ks < 8; ks++) {
            int k0 = ks * 32 + quad * 8;
            bf16x8 bb[4];
#pragma unroll
            for (int nt = 0; nt < 4; nt++)
                bb[nt] = *(const bf16x8*)(Xb + (4 * l15 + nt) * 256 + (k0 ^ ((l15 & 7) << 3)));
            bf16x8 aK[2], aV[2];
#pragma unroll
            for (int mt = 0; mt < 2; mt++) {
                size_t off = (size_t)(rbase + mt * 16 + l15) * 256 + k0;
                aK[mt] = *(const bf16x8*)(wkb + off);
                aV[mt] = *(const bf16x8*)(wvb + off);
            }
#pragma unroll
            for (int mt = 0; mt < 2; mt++)
#pragma unroll
                for (int nt = 0; nt < 4; nt++) {
                    ak[mt][nt] = __builtin_amdgcn_mfma_f32_16x16x32_bf16(aK[mt], bb[nt], ak[mt][nt], 0, 0, 0);
                    av[mt][nt] = __builtin_amdgcn_mfma_f32_16x16x32_bf16(aV[mt], bb[nt], av[mt][nt], 0, 0, 0);
                }
        }
        // epilogue: p = exp(k + bk) -> Pl, v + bv -> Vl (b64 writes), rowsum in regs
#pragma unroll
        for (int mt = 0; mt < 2; mt++)
#pragma unroll
            for (int r = 0; r < 4; r++) {
                int row = rbase + mt * 16 + quad * 4 + r;
                float bK = bkr[mt][r], bV = bvr[mt][r];
                float e0 = __expf(ak[mt][0][r] + bK);
                float e1 = __expf(ak[mt][1][r] + bK);
                float e2 = __expf(ak[mt][2][r] + bK);
                float e3 = __expf(ak[mt][3][r] + bK);
                rs_acc[mt][r] += e0 + e1 + e2 + e3;
                int pa = row * 64 + ((4 * l15) ^ ((row & 7) << 3));
                bf16x4 pk = {(__bf16)e0, (__bf16)e1, (__bf16)e2, (__bf16)e3};
                *(bf16x4*)(Pl + pa) = pk;
                bf16x4 vk = {(__bf16)(av[mt][0][r] + bV), (__bf16)(av[mt][1][r] + bV),
                             (__bf16)(av[mt][2][r] + bV), (__bf16)(av[mt][3][r] + bV)};
                *(bf16x4*)(Vl + pa) = vk;
            }
        __syncthreads();
        // write next X tile (regs -> LDS) while ctx MFMAs run
        if (tt < 7) {
            __bf16* Xn = Xl + (buf ^ 1) * (64 * 256);
#pragma unroll
            for (int i = 0; i < 8; i++) {
                int ca = (cg * 8 + i) ^ xswz;
#pragma unroll
                for (int j = 0; j < 4; j++)
                    Xn[(4 * sl + j) * 256 + ca] = (__bf16)xr[i][j];
            }
        }
        // ctx quadrant: cacc += p[prow0..+63][px] @ v[vrow0..+63][px]^T, K=64
#pragma unroll
        for (int ks = 0; ks < 2; ks++) {
            int k0 = ks * 32 + quad * 8;
            bf16x8 pfr[4], vfr[4];
#pragma unroll
            for (int mt = 0; mt < 4; mt++) {
                int row = prow0 + mt * 16 + l15;
                pfr[mt] = *(const bf16x8*)(Pl + row * 64 + (k0 ^ ((row & 7) << 3)));
            }
#pragma unroll
            for (int nt = 0; nt < 4; nt++) {
                int row = vrow0 + nt * 16 + l15;
                vfr[nt] = *(const bf16x8*)(Vl + row * 64 + (k0 ^ ((row & 7) << 3)));
            }
#pragma unroll
            for (int mt = 0; mt < 4; mt++)
#pragma unroll
                for (int nt = 0; nt < 4; nt++)
                    cacc[mt][nt] = __builtin_amdgcn_mfma_f32_16x16x32_bf16(pfr[mt], vfr[nt], cacc[mt][nt], 0, 0, 0);
        }
        __syncthreads();
        buf ^= 1;
    }
    // flush rowsum: reduce over the 16 px-lanes, one atomic per row
#pragma unroll
    for (int mt = 0; mt < 2; mt++)
#pragma unroll
        for (int r = 0; r < 4; r++) {
            float v = rs_acc[mt][r];
            v += __shfl_xor(v, 1);
            v += __shfl_xor(v, 2);
            v += __shfl_xor(v, 4);
            v += __shfl_xor(v, 8);
            if (l15 == 0)
                atomicAdd(rowsum + b * CH + rbase + mt * 16 + quad * 4 + r, v);
        }
    // flush ctx
    float* cb = ctx + ((size_t)b * 2 + head) * 16384;
#pragma unroll
    for (int mt = 0; mt < 4; mt++)
#pragma unroll
        for (int nt = 0; nt < 4; nt++)
#pragma unroll
            for (int r = 0; r < 4; r++) {
                int kk = rh * 64 + mt * 16 + quad * 4 + r;
                int vv = chh * 64 + nt * 16 + l15;
                atomicAdd(cb + kk * 128 + vv, cacc[mt][nt][r]);
            }
}

// ---- normalize ctx rows by rowsum, compute pooled mean ----
__global__ void ea_normpool(float* ctx, const float* rowsum, float* pooled) {
    __shared__ float sm[8];
    int bi = blockIdx.x, b = bi >> 1, h = bi & 1;
    float* base = ctx + (size_t)bi * 16384;
    const float* rs = rowsum + b * CH + h * 128;
    float sum = 0.f, dummy = 0.f;
    for (int i = threadIdx.x; i < 16384; i += 256) {
        float v = base[i] / rs[i >> 7];
        base[i] = v;
        sum += v;
    }
    blockReduce2(sum, dummy, sm);
    if (threadIdx.x == 0) pooled[bi] = sum * (1.f / 16384.f);
}

// ---- SE gate + fold w_rep ----
__global__ __launch_bounds__(256) void ea_M(const float* ctx, const float* pooled,
                                            const float* wfc1, const float* bfc1,
                                            const float* wfc2, const float* bfc2,
                                            const float* wse, const float* bse,
                                            const float* wrep, __bf16* Mbf) {
    __shared__ float L[128 * 128];
    int bi = blockIdx.x, b = bi >> 3, h = (bi >> 2) & 1, strip = bi & 3;
    float p0 = pooled[b * 2], p1 = pooled[b * 2 + 1];
    float z10 = fmaxf(0.f, wfc1[0] * p0 + wfc1[1] * p1 + bfc1[0]);
    float z11 = fmaxf(0.f, wfc1[2] * p0 + wfc1[3] * p1 + bfc1[1]);
    float z20 = wfc2[0] * z10 + wfc2[1] * z11 + bfc2[0];
    float z21 = wfc2[2] * z10 + wfc2[3] * z11 + bfc2[1];
    float g0 = 1.f / (1.f + __expf(-z20)), g1 = 1.f / (1.f + __expf(-z21));
    float a0 = wse[0] * g0, a1 = wse[1] * g1, bs = bse[0];
    const float* c0 = ctx + (size_t)b * 2 * 16384;
    const float* c1 = c0 + 16384;
    for (int i = threadIdx.x; i < 16384; i += 256) L[i] = a0 * c0[i] + a1 * c1[i] + bs;
    __syncthreads();
    int o = strip * 64 + (threadIdx.x & 63), kb = (threadIdx.x >> 6) * 32;
    const float4* wr = (const float4*)(wrep + (size_t)o * 256 + h * 128);
    for (int kk = kb; kk < kb + 32; kk++) {
        const float4* Lr = (const float4*)(L + kk * 128);
        float acc = 0.f;
#pragma unroll 8
        for (int j = 0; j < 32; j++) {
            float4 w4 = wr[j];
            float4 l4 = Lr[j];
            acc += w4.x * l4.x + w4.y * l4.y + w4.z * l4.z + w4.w * l4.w;
        }
        Mbf[(size_t)(b * 256 + o) * 256 + h * 128 + kk] = (__bf16)acc;
    }
}

// stage raw x tile into LDS as swizzled [px][ch] bf16 (ea_final)
__device__ __forceinline__ void stage_x(const float* xb, __bf16* Xl, int t) {
    int l15 = t & 15, c0 = t >> 4;
    const float* xp = xb + l15 * 4;
    int hbase = (l15 * 4) * PITCH;
#pragma unroll
    for (int i = 0; i < 16; i++) {
        int c = c0 * 16 + i;
        float4 v = *(const float4*)(xp + (size_t)c * SPAT);
        Xl[lswz(hbase + c)]             = (__bf16)v.x;
        Xl[lswz(hbase + PITCH + c)]     = (__bf16)v.y;
        Xl[lswz(hbase + 2 * PITCH + c)] = (__bf16)v.z;
        Xl[lswz(hbase + 3 * PITCH + c)] = (__bf16)v.w;
    }
}

// per-wave 64x64 strip of a [256 x 64px] GEMM, K=256 (ea_final)
__device__ __forceinline__ void mm256(const __bf16* __restrict__ A, const __bf16* Xl,
                                      int WB, int quad, int l15, f32x4 (&acc)[4][4]) {
#pragma unroll 2
    for (int ks = 0; ks < 8; ks++) {
        int k0 = ks * 32;
        bf16x8 a[4];
#pragma unroll
        for (int mt = 0; mt < 4; mt++)
            a[mt] = *(const bf16x8*)(A + (WB + mt * 16 + l15) * 256 + k0 + quad * 8);
        bf16x8 bb[4];
#pragma unroll
        for (int nt = 0; nt < 4; nt++)
            bb[nt] = *(const bf16x8*)(Xl + lswz((4 * l15 + nt) * PITCH + k0 + quad * 8));
#pragma unroll
        for (int mt = 0; mt < 4; mt++)
#pragma unroll
            for (int nt = 0; nt < 4; nt++)
                acc[mt][nt] = __builtin_amdgcn_mfma_f32_16x16x32_bf16(a[mt], bb[nt], acc[mt][nt], 0, 0, 0);
    }
}

// ---- final: q = wq'@x+bq', channel-softmax per head, out = M@qsoft + b_rep ----
__global__ __launch_bounds__(256) void ea_final(const float* __restrict__ x,
        const __bf16* __restrict__ wqb, const float* __restrict__ bqf,
        const __bf16* __restrict__ Mbf, const float* __restrict__ brep, float* __restrict__ out) {
    __shared__ __bf16 X[TP * PITCH];
    __shared__ __bf16 Q[TP * PITCH];
    __shared__ float psum[256];
    __shared__ float rcp[TP * 2];
    int bi = blockIdx.x, b = bi >> 8, s0 = (bi & 255) * TP, t = threadIdx.x;
    stage_x(x + (size_t)b * CH * SPAT + s0, X, t);
    __syncthreads();

    int lane = t & 63, wave = t >> 6, quad = lane >> 4, l15 = lane & 15, WB = wave * 64;
    const f32x4 z = {0.f, 0.f, 0.f, 0.f};

    // matmul1: q-logits -> exp -> Q[px][ch]
    {
        f32x4 acc[4][4];
#pragma unroll
        for (int mt = 0; mt < 4; mt++)
#pragma unroll
            for (int nt = 0; nt < 4; nt++) acc[mt][nt] = z;
        mm256(wqb, X, WB, quad, l15, acc);
#pragma unroll
        for (int mt = 0; mt < 4; mt++) {
            int row0 = WB + mt * 16 + quad * 4;
#pragma unroll
            for (int nt = 0; nt < 4; nt++) {
                bf16x4 qk;
#pragma unroll
                for (int r = 0; r < 4; r++)
                    qk[r] = (__bf16)__expf(acc[mt][nt][r] + bqf[row0 + r]);
                *(bf16x4*)(Q + lswz((4 * l15 + nt) * PITCH + row0)) = qk;
            }
        }
    }
    __syncthreads();
    // column sums per (px, head)
    {
        int px = t & 63, hh = (t >> 6) & 1, part = t >> 7;
        int cb = hh * 128 + part * 64;
        float s = 0.f;
#pragma unroll
        for (int j = 0; j < 8; j++) {
            bf16x8 qv = *(const bf16x8*)(Q + lswz(px * PITCH + cb + j * 8));
#pragma unroll
            for (int e = 0; e < 8; e++) s += (float)qv[e];
        }
        psum[t] = s;
    }
    __syncthreads();
    if (t < 128) {
        float tot = psum[t] + psum[t + 128];
        rcp[(t & 63) * 2 + (t >> 6)] = 1.f / tot;
    }
    __syncthreads();
    // normalize Q in place
#pragma unroll 2
    for (int e = t; e < TP * 32; e += 256) {
        int px = e >> 5, cc = (e & 31) * 8;
        float sc = rcp[px * 2 + (cc >> 7)];
        int h = lswz(px * PITCH + cc);
        bf16x8 qv = *(const bf16x8*)(Q + h);
        bf16x8 qo;
#pragma unroll
        for (int j2 = 0; j2 < 8; j2++) qo[j2] = (__bf16)((float)qv[j2] * sc);
        *(bf16x8*)(Q + h) = qo;
    }
    __syncthreads();
    // matmul2: out = M @ qsoft + b_rep
    {
        f32x4 acc[4][4];
#pragma unroll
        for (int mt = 0; mt < 4; mt++)
#pragma unroll
            for (int nt = 0; nt < 4; nt++) acc[mt][nt] = z;
        mm256(Mbf + (size_t)b * 65536, Q, WB, quad, l15, acc);
#pragma unroll
        for (int mt = 0; mt < 4; mt++) {
            int row0 = WB + mt * 16 + quad * 4;
#pragma unroll
            for (int r = 0; r < 4; r++) {
                int row = row0 + r;
                float bs = brep[row];
                f32x4 o4 = {acc[mt][0][r] + bs, acc[mt][1][r] + bs,
                            acc[mt][2][r] + bs, acc[mt][3][r] + bs};
                *(f32x4*)(out + (size_t)(b * CH + row) * SPAT + s0 + 4 * l15) = o4;
            }
        }
    }
}

extern "C" void kernel_launch(void* const* d_in, const int* in_sizes, int n_in,
                              void* d_out, int out_size, void* d_ws, size_t ws_size,
                              hipStream_t stream) {
    (void)in_sizes; (void)n_in; (void)out_size; (void)ws_size;
    const float* x     = (const float*)d_in[0];
    const float* gamma = (const float*)d_in[1];
    const float* beta  = (const float*)d_in[2];
    const float* wk    = (const float*)d_in[3];
    const float* bk    = (const float*)d_in[4];
    const float* wq    = (const float*)d_in[5];
    const float* bq    = (const float*)d_in[6];
    const float* wv    = (const float*)d_in[7];
    const float* bv    = (const float*)d_in[8];
    const float* wfc1  = (const float*)d_in[9];
    const float* bfc1  = (const float*)d_in[10];
    const float* wfc2  = (const float*)d_in[11];
    const float* bfc2  = (const float*)d_in[12];
    const float* wse   = (const float*)d_in[13];
    const float* bse   = (const float*)d_in[14];
    const float* wrep  = (const float*)d_in[15];
    const float* brep  = (const float*)d_in[16];

    float* ws = (float*)d_ws;
    __bf16* wkb = (__bf16*)(ws + WS_WKBF);
    __bf16* wqb = (__bf16*)(ws + WS_WQBF);
    __bf16* wvb = (__bf16*)(ws + WS_WVBF);
    __bf16* Mbf = (__bf16*)(ws + WS_MBF);
    float* out = (float*)d_out;

    hipMemsetAsync((void*)(ws + WS_ROWSUM), 0,
                   (size_t)(WS_MBF - WS_ROWSUM) * sizeof(float), stream);
    ea_bnstats<<<2048, 256, 0, stream>>>(x, ws + WS_SUM, ws + WS_SSUM);
    ea_fold<<<256, 256, 0, stream>>>(wk, wq, wv, bk, bq, bv, gamma, beta,
                                     ws + WS_SUM, ws + WS_SSUM,
                                     wkb, wqb, wvb, ws + WS_BKF, ws + WS_BQF, ws + WS_BVF);
    ea_kvctx<<<256, 512, 0, stream>>>(x, wkb, wvb, ws + WS_BKF, ws + WS_BVF,
                                      ws + WS_CTX, ws + WS_ROWSUM);
    ea_normpool<<<16, 256, 0, stream>>>(ws + WS_CTX, ws + WS_ROWSUM, ws + WS_POOLED);
    ea_M<<<64, 256, 0, stream>>>(ws + WS_CTX, ws + WS_POOLED, wfc1, bfc1, wfc2, bfc2,
                                 wse, bse, wrep, Mbf);
    ea_final<<<2048, 256, 0, stream>>>(x, wqb, ws + WS_BQF, Mbf, brep, out);
}

// Round 3
// 593.656 us; speedup vs baseline: 1.2667x; 1.0190x over previous
//
#include <hip/hip_runtime.h>
#include <hip/hip_bf16.h>

#define BATCH 8
#define CH 256
#define SPAT 16384
#define TP 64       // pixel tile
#define PITCH 272   // (ea_final only) LDS channel pitch in halfwords

typedef __attribute__((ext_vector_type(4))) float f32x4;
typedef __attribute__((ext_vector_type(8))) __bf16 bf16x8;
typedef __attribute__((ext_vector_type(4))) __bf16 bf16x4;

// workspace float offsets
#define WS_ROWSUM  512      // 2048  (zeroed)
#define WS_POOLED  2560     // 16   (zeroed)
#define WS_BKF     2576     // 256 folded biases
#define WS_BQF     2832
#define WS_BVF     3088
#define WS_SUM     3344     // 256 (zeroed)
#define WS_SSUM    3600     // 256 (zeroed)
#define WS_CTX     4096     // 16*128*128 = 262144 (written whole by ea_ctxred)
#define WS_MBF     266240   // 8*256*256 bf16 = 262144 floats
#define WS_WKBF    528384   // 65536 bf16 = 32768 floats
#define WS_WQBF    561152
#define WS_WVBF    593920

// (ea_final only) bijective LDS swizzle on halfword index
__device__ __forceinline__ int lswz(int h) { return h ^ (((h >> 7) & 7) << 3); }

__device__ __forceinline__ void blockReduce2(float& a, float& b, volatile float* sm) {
    int lane = threadIdx.x & 63, w = threadIdx.x >> 6;
#pragma unroll
    for (int o = 32; o; o >>= 1) { a += __shfl_down(a, o); b += __shfl_down(b, o); }
    if (lane == 0) { sm[w] = a; sm[4 + w] = b; }
    __syncthreads();
    if (threadIdx.x == 0) {
        a = sm[0] + sm[1] + sm[2] + sm[3];
        b = sm[4] + sm[5] + sm[6] + sm[7];
    }
}

// ---- BN batch stats: per-(b,c) partial sums, atomically accumulated ----
__global__ __launch_bounds__(256) void ea_bnstats(const float* __restrict__ x,
                                                  float* sums, float* ssums) {
    __shared__ float sm[8];
    int bi = blockIdx.x, c = bi >> 3, b = bi & 7;
    const float4* p = (const float4*)(x + (size_t)(b * CH + c) * SPAT);
    float sum = 0.f, ss = 0.f;
    for (int i = threadIdx.x; i < SPAT / 4; i += 256) {
        float4 v = p[i];
        sum += v.x + v.y + v.z + v.w;
        ss  += v.x * v.x + v.y * v.y + v.z * v.z + v.w * v.w;
    }
    blockReduce2(sum, ss, sm);
    if (threadIdx.x == 0) { atomicAdd(sums + c, sum); atomicAdd(ssums + c, ss); }
}

// ---- fold BN scale/shift into bf16 weights + fp32 biases ----
__global__ __launch_bounds__(256) void ea_fold(const float* __restrict__ wk, const float* __restrict__ wq,
        const float* __restrict__ wv, const float* __restrict__ bk, const float* __restrict__ bq,
        const float* __restrict__ bv, const float* __restrict__ gamma, const float* __restrict__ beta,
        const float* __restrict__ sums, const float* __restrict__ ssums,
        __bf16* wkb, __bf16* wqb, __bf16* wvb, float* bkf, float* bqf, float* bvf) {
    __shared__ float sm[12];
    int o = blockIdx.x, c = threadIdx.x;
    const float inv = 1.f / (float)(BATCH * SPAT);
    float mean = sums[c] * inv;
    float var  = ssums[c] * inv - mean * mean;
    float sc   = gamma[c] * rsqrtf(var + 1e-5f);
    float sh   = beta[c] - mean * sc;
    float k = wk[o * 256 + c], q = wq[o * 256 + c], v = wv[o * 256 + c];
    wkb[o * 256 + c] = (__bf16)(k * sc);
    wqb[o * 256 + c] = (__bf16)(q * sc);
    wvb[o * 256 + c] = (__bf16)(v * sc);
    float ak = k * sh, aq = q * sh, av = v * sh;
    int lane = c & 63, w = c >> 6;
#pragma unroll
    for (int off = 32; off; off >>= 1) {
        ak += __shfl_down(ak, off);
        aq += __shfl_down(aq, off);
        av += __shfl_down(av, off);
    }
    if (lane == 0) { sm[w] = ak; sm[4 + w] = aq; sm[8 + w] = av; }
    __syncthreads();
    if (c == 0) {
        bkf[o] = bk[o] + sm[0] + sm[1] + sm[2] + sm[3];
        bqf[o] = bq[o] + sm[4] + sm[5] + sm[6] + sm[7];
        bvf[o] = bv[o] + sm[8] + sm[9] + sm[10] + sm[11];
    }
}

// ---- fused K/V projection + context accumulation ----
// 256 blocks = (batch b, 512-px chunk); 512 threads = 8 waves; 8 tiles of 64 px.
// ctx partials go to PRIVATE per-block slices (plain stores) — no cross-XCD atomics.
__global__ __launch_bounds__(512, 2) void ea_kvctx(const float* __restrict__ x,
        const __bf16* __restrict__ wkb, const __bf16* __restrict__ wvb,
        const float* __restrict__ bkf, const float* __restrict__ bvf,
        float* __restrict__ ctxpart, float* __restrict__ rowsum) {
    __shared__ __bf16 Xl[2 * 64 * 256];   // 64 KB double-buffered x tile
    __shared__ __bf16 Pl[256 * 64];       // 32 KB p = exp(k) tile
    __shared__ __bf16 Vl[256 * 64];       // 32 KB v tile
    const int bi = blockIdx.x, b = bi >> 5, chunk = bi & 31;
    const int t = threadIdx.x;
    const int lane = t & 63, wave = t >> 6, quad = lane >> 4, l15 = lane & 15;
    const int rbase = wave * 32;              // proj output rows for this wave
    const int sl = t & 15, cg = t >> 4;       // staging: px0 = 4*sl, c = cg*8 + i
    const int xswz = (sl & 7) << 3;
    const float* xp0 = x + (size_t)(b * CH + cg * 8) * SPAT + chunk * 512 + 4 * sl;

    float bkr[2][4], bvr[2][4];
#pragma unroll
    for (int mt = 0; mt < 2; mt++)
#pragma unroll
        for (int r = 0; r < 4; r++) {
            int row = rbase + mt * 16 + quad * 4 + r;
            bkr[mt][r] = bkf[row];
            bvr[mt][r] = bvf[row];
        }

    const f32x4 z = {0.f, 0.f, 0.f, 0.f};
    f32x4 cacc[4][4];
#pragma unroll
    for (int vt = 0; vt < 4; vt++)
#pragma unroll
        for (int kt = 0; kt < 4; kt++) cacc[vt][kt] = z;
    float rs_acc[2][4] = {{0.f, 0.f, 0.f, 0.f}, {0.f, 0.f, 0.f, 0.f}};

    const int head = wave >> 2, rh = (wave >> 1) & 1, chh = wave & 1;
    const int prow0 = head * 128 + rh * 64, vrow0 = head * 128 + chh * 64;

    // prologue: stage tile 0
    f32x4 xr[8];
#pragma unroll
    for (int i = 0; i < 8; i++) xr[i] = *(const f32x4*)(xp0 + (size_t)i * SPAT);
#pragma unroll
    for (int i = 0; i < 8; i++) {
        int ca = (cg * 8 + i) ^ xswz;
#pragma unroll
        for (int j = 0; j < 4; j++)
            Xl[(4 * sl + j) * 256 + ca] = (__bf16)xr[i][j];
    }
    __syncthreads();

    int buf = 0;
    for (int tt = 0; tt < 8; tt++) {
        // fused K+V projection: 32 rows x 64 px, K=256; B-frags shared between K and V
        const __bf16* Xb = Xl + buf * (64 * 256);
        f32x4 ak[2][4], av[2][4];
#pragma unroll
        for (int mt = 0; mt < 2; mt++)
#pragma unroll
            for (int nt = 0; nt < 4; nt++) { ak[mt][nt] = z; av[mt][nt] = z; }
#pragma unroll 2
        for (int ks = 0; ks < 8; ks++) {
            int k0 = ks * 32 + quad * 8;
            bf16x8 bb[4];
#pragma unroll
            for (int nt = 0; nt < 4; nt++)
                bb[nt] = *(const bf16x8*)(Xb + (4 * l15 + nt) * 256 + (k0 ^ ((l15 & 7) << 3)));
            bf16x8 aK[2], aV[2];
#pragma unroll
            for (int mt = 0; mt < 2; mt++) {
                size_t off = (size_t)(rbase + mt * 16 + l15) * 256 + k0;
                aK[mt] = *(const bf16x8*)(wkb + off);
                aV[mt] = *(const bf16x8*)(wvb + off);
            }
#pragma unroll
            for (int mt = 0; mt < 2; mt++)
#pragma unroll
                for (int nt = 0; nt < 4; nt++) {
                    ak[mt][nt] = __builtin_amdgcn_mfma_f32_16x16x32_bf16(aK[mt], bb[nt], ak[mt][nt], 0, 0, 0);
                    av[mt][nt] = __builtin_amdgcn_mfma_f32_16x16x32_bf16(aV[mt], bb[nt], av[mt][nt], 0, 0, 0);
                }
        }
        // issue next tile's global loads AFTER proj (so proj's weight-load waits
        // don't drain them); they land during epilogue+barrier+ctx (~>900cy)
        if (tt < 7) {
            const float* xp = xp0 + (tt + 1) * 64;
#pragma unroll
            for (int i = 0; i < 8; i++) xr[i] = *(const f32x4*)(xp + (size_t)i * SPAT);
        }
        // epilogue: p = exp(k + bk) -> Pl, v + bv -> Vl, rowsum in regs
#pragma unroll
        for (int mt = 0; mt < 2; mt++)
#pragma unroll
            for (int r = 0; r < 4; r++) {
                int row = rbase + mt * 16 + quad * 4 + r;
                float bK = bkr[mt][r], bV = bvr[mt][r];
                float e0 = __expf(ak[mt][0][r] + bK);
                float e1 = __expf(ak[mt][1][r] + bK);
                float e2 = __expf(ak[mt][2][r] + bK);
                float e3 = __expf(ak[mt][3][r] + bK);
                rs_acc[mt][r] += e0 + e1 + e2 + e3;
                int pa = row * 64 + ((4 * l15) ^ ((row & 7) << 3));
                bf16x4 pk = {(__bf16)e0, (__bf16)e1, (__bf16)e2, (__bf16)e3};
                *(bf16x4*)(Pl + pa) = pk;
                bf16x4 vk = {(__bf16)(av[mt][0][r] + bV), (__bf16)(av[mt][1][r] + bV),
                             (__bf16)(av[mt][2][r] + bV), (__bf16)(av[mt][3][r] + bV)};
                *(bf16x4*)(Vl + pa) = vk;
            }
        __syncthreads();
        // ctx quadrant, SWAPPED operands: cacc[vt][kt] rows=vv, cols=kk
        // -> coalesced f32x4 partial stores at flush (r contiguous in vv)
#pragma unroll
        for (int ks = 0; ks < 2; ks++) {
            int k0 = ks * 32 + quad * 8;
            bf16x8 pfr[4], vfr[4];
#pragma unroll
            for (int kt = 0; kt < 4; kt++) {
                int row = prow0 + kt * 16 + l15;
                pfr[kt] = *(const bf16x8*)(Pl + row * 64 + (k0 ^ ((row & 7) << 3)));
            }
#pragma unroll
            for (int vt = 0; vt < 4; vt++) {
                int row = vrow0 + vt * 16 + l15;
                vfr[vt] = *(const bf16x8*)(Vl + row * 64 + (k0 ^ ((row & 7) << 3)));
            }
#pragma unroll
            for (int vt = 0; vt < 4; vt++)
#pragma unroll
                for (int kt = 0; kt < 4; kt++)
                    cacc[vt][kt] = __builtin_amdgcn_mfma_f32_16x16x32_bf16(vfr[vt], pfr[kt], cacc[vt][kt], 0, 0, 0);
        }
        // write next X tile (regs -> LDS) after ctx reads; loads have drained by now
        if (tt < 7) {
            __bf16* Xn = Xl + (buf ^ 1) * (64 * 256);
#pragma unroll
            for (int i = 0; i < 8; i++) {
                int ca = (cg * 8 + i) ^ xswz;
#pragma unroll
                for (int j = 0; j < 4; j++)
                    Xn[(4 * sl + j) * 256 + ca] = (__bf16)xr[i][j];
            }
        }
        __syncthreads();
        buf ^= 1;
    }
    // flush rowsum: reduce over the 16 px-lanes, one atomic per row (tiny: 256/block)
#pragma unroll
    for (int mt = 0; mt < 2; mt++)
#pragma unroll
        for (int r = 0; r < 4; r++) {
            float v = rs_acc[mt][r];
            v += __shfl_xor(v, 1);
            v += __shfl_xor(v, 2);
            v += __shfl_xor(v, 4);
            v += __shfl_xor(v, 8);
            if (l15 == 0)
                atomicAdd(rowsum + b * CH + rbase + mt * 16 + quad * 4 + r, v);
        }
    // flush ctx partials: PLAIN coalesced stores to private slice [kk][vv]
    float* pbase = ctxpart + (((size_t)(b * 32 + chunk)) * 2 + head) * 16384;
#pragma unroll
    for (int vt = 0; vt < 4; vt++)
#pragma unroll
        for (int kt = 0; kt < 4; kt++) {
            int kk = rh * 64 + kt * 16 + l15;
            int vv = chh * 64 + vt * 16 + quad * 4;
            *(f32x4*)(pbase + kk * 128 + vv) = cacc[vt][kt];
        }
}

// ---- reduce ctx partials over 32 chunks, normalize by rowsum, pooled partial ----
__global__ __launch_bounds__(256) void ea_ctxred(const float* __restrict__ part,
        const float* __restrict__ rowsum, float* __restrict__ ctx, float* __restrict__ pooled) {
    __shared__ float sm[8];
    int bi = blockIdx.x, b = bi >> 5, h = (bi >> 4) & 1, ks = bi & 15;
    int t = threadIdx.x;
    int kk = ks * 8 + (t >> 5), vv = (t & 31) * 4;
    const float* p0 = part + (((size_t)b * 32) * 2 + h) * 16384 + (size_t)kk * 128 + vv;
    f32x4 acc = {0.f, 0.f, 0.f, 0.f};
#pragma unroll 4
    for (int c = 0; c < 32; c++) {
        f32x4 v = *(const f32x4*)(p0 + (size_t)c * 32768);
        acc[0] += v[0]; acc[1] += v[1]; acc[2] += v[2]; acc[3] += v[3];
    }
    float inv = 1.f / rowsum[b * CH + h * 128 + kk];
    f32x4 o = {acc[0] * inv, acc[1] * inv, acc[2] * inv, acc[3] * inv};
    *(f32x4*)(ctx + ((size_t)b * 2 + h) * 16384 + (size_t)kk * 128 + vv) = o;
    float s = o[0] + o[1] + o[2] + o[3], d = 0.f;
    blockReduce2(s, d, sm);
    if (t == 0) atomicAdd(pooled + b * 2 + h, s);
}

// ---- SE gate + fold w_rep ----
__global__ __launch_bounds__(256) void ea_M(const float* ctx, const float* pooled,
                                            const float* wfc1, const float* bfc1,
                                            const float* wfc2, const float* bfc2,
                                            const float* wse, const float* bse,
                                            const float* wrep, __bf16* Mbf) {
    __shared__ float L[128 * 128];
    int bi = blockIdx.x, b = bi >> 3, h = (bi >> 2) & 1, strip = bi & 3;
    float p0 = pooled[b * 2] * (1.f / 16384.f), p1 = pooled[b * 2 + 1] * (1.f / 16384.f);
    float z10 = fmaxf(0.f, wfc1[0] * p0 + wfc1[1] * p1 + bfc1[0]);
    float z11 = fmaxf(0.f, wfc1[2] * p0 + wfc1[3] * p1 + bfc1[1]);
    float z20 = wfc2[0] * z10 + wfc2[1] * z11 + bfc2[0];
    float z21 = wfc2[2] * z10 + wfc2[3] * z11 + bfc2[1];
    float g0 = 1.f / (1.f + __expf(-z20)), g1 = 1.f / (1.f + __expf(-z21));
    float a0 = wse[0] * g0, a1 = wse[1] * g1, bs = bse[0];
    const float* c0 = ctx + (size_t)b * 2 * 16384;
    const float* c1 = c0 + 16384;
    for (int i = threadIdx.x; i < 16384; i += 256) L[i] = a0 * c0[i] + a1 * c1[i] + bs;
    __syncthreads();
    int o = strip * 64 + (threadIdx.x & 63), kb = (threadIdx.x >> 6) * 32;
    const float4* wr = (const float4*)(wrep + (size_t)o * 256 + h * 128);
    for (int kk = kb; kk < kb + 32; kk++) {
        const float4* Lr = (const float4*)(L + kk * 128);
        float acc = 0.f;
#pragma unroll 8
        for (int j = 0; j < 32; j++) {
            float4 w4 = wr[j];
            float4 l4 = Lr[j];
            acc += w4.x * l4.x + w4.y * l4.y + w4.z * l4.z + w4.w * l4.w;
        }
        Mbf[(size_t)(b * 256 + o) * 256 + h * 128 + kk] = (__bf16)acc;
    }
}

// stage raw x tile into LDS as swizzled [px][ch] bf16 (ea_final)
__device__ __forceinline__ void stage_x(const float* xb, __bf16* Xl, int t) {
    int l15 = t & 15, c0 = t >> 4;
    const float* xp = xb + l15 * 4;
    int hbase = (l15 * 4) * PITCH;
#pragma unroll
    for (int i = 0; i < 16; i++) {
        int c = c0 * 16 + i;
        float4 v = *(const float4*)(xp + (size_t)c * SPAT);
        Xl[lswz(hbase + c)]             = (__bf16)v.x;
        Xl[lswz(hbase + PITCH + c)]     = (__bf16)v.y;
        Xl[lswz(hbase + 2 * PITCH + c)] = (__bf16)v.z;
        Xl[lswz(hbase + 3 * PITCH + c)] = (__bf16)v.w;
    }
}

// per-wave 64x64 strip of a [256 x 64px] GEMM, K=256 (ea_final)
__device__ __forceinline__ void mm256(const __bf16* __restrict__ A, const __bf16* Xl,
                                      int WB, int quad, int l15, f32x4 (&acc)[4][4]) {
#pragma unroll 2
    for (int ks = 0; ks < 8; ks++) {
        int k0 = ks * 32;
        bf16x8 a[4];
#pragma unroll
        for (int mt = 0; mt < 4; mt++)
            a[mt] = *(const bf16x8*)(A + (WB + mt * 16 + l15) * 256 + k0 + quad * 8);
        bf16x8 bb[4];
#pragma unroll
        for (int nt = 0; nt < 4; nt++)
            bb[nt] = *(const bf16x8*)(Xl + lswz((4 * l15 + nt) * PITCH + k0 + quad * 8));
#pragma unroll
        for (int mt = 0; mt < 4; mt++)
#pragma unroll
            for (int nt = 0; nt < 4; nt++)
                acc[mt][nt] = __builtin_amdgcn_mfma_f32_16x16x32_bf16(a[mt], bb[nt], acc[mt][nt], 0, 0, 0);
    }
}

// ---- final: q = wq'@x+bq', channel-softmax per head, out = M@qsoft + b_rep ----
__global__ __launch_bounds__(256) void ea_final(const float* __restrict__ x,
        const __bf16* __restrict__ wqb, const float* __restrict__ bqf,
        const __bf16* __restrict__ Mbf, const float* __restrict__ brep, float* __restrict__ out) {
    __shared__ __bf16 X[TP * PITCH];
    __shared__ __bf16 Q[TP * PITCH];
    __shared__ float psum[256];
    __shared__ float rcp[TP * 2];
    int bi = blockIdx.x, b = bi >> 8, s0 = (bi & 255) * TP, t = threadIdx.x;
    stage_x(x + (size_t)b * CH * SPAT + s0, X, t);
    __syncthreads();

    int lane = t & 63, wave = t >> 6, quad = lane >> 4, l15 = lane & 15, WB = wave * 64;
    const f32x4 z = {0.f, 0.f, 0.f, 0.f};

    // matmul1: q-logits -> exp -> Q[px][ch]
    {
        f32x4 acc[4][4];
#pragma unroll
        for (int mt = 0; mt < 4; mt++)
#pragma unroll
            for (int nt = 0; nt < 4; nt++) acc[mt][nt] = z;
        mm256(wqb, X, WB, quad, l15, acc);
#pragma unroll
        for (int mt = 0; mt < 4; mt++) {
            int row0 = WB + mt * 16 + quad * 4;
#pragma unroll
            for (int nt = 0; nt < 4; nt++) {
                bf16x4 qk;
#pragma unroll
                for (int r = 0; r < 4; r++)
                    qk[r] = (__bf16)__expf(acc[mt][nt][r] + bqf[row0 + r]);
                *(bf16x4*)(Q + lswz((4 * l15 + nt) * PITCH + row0)) = qk;
            }
        }
    }
    __syncthreads();
    // column sums per (px, head)
    {
        int px = t & 63, hh = (t >> 6) & 1, part = t >> 7;
        int cb = hh * 128 + part * 64;
        float s = 0.f;
#pragma unroll
        for (int j = 0; j < 8; j++) {
            bf16x8 qv = *(const bf16x8*)(Q + lswz(px * PITCH + cb + j * 8));
#pragma unroll
            for (int e = 0; e < 8; e++) s += (float)qv[e];
        }
        psum[t] = s;
    }
    __syncthreads();
    if (t < 128) {
        float tot = psum[t] + psum[t + 128];
        rcp[(t & 63) * 2 + (t >> 6)] = 1.f / tot;
    }
    __syncthreads();
    // normalize Q in place
#pragma unroll 2
    for (int e = t; e < TP * 32; e += 256) {
        int px = e >> 5, cc = (e & 31) * 8;
        float sc = rcp[px * 2 + (cc >> 7)];
        int h = lswz(px * PITCH + cc);
        bf16x8 qv = *(const bf16x8*)(Q + h);
        bf16x8 qo;
#pragma unroll
        for (int j2 = 0; j2 < 8; j2++) qo[j2] = (__bf16)((float)qv[j2] * sc);
        *(bf16x8*)(Q + h) = qo;
    }
    __syncthreads();
    // matmul2: out = M @ qsoft + b_rep
    {
        f32x4 acc[4][4];
#pragma unroll
        for (int mt = 0; mt < 4; mt++)
#pragma unroll
            for (int nt = 0; nt < 4; nt++) acc[mt][nt] = z;
        mm256(Mbf + (size_t)b * 65536, Q, WB, quad, l15, acc);
#pragma unroll
        for (int mt = 0; mt < 4; mt++) {
            int row0 = WB + mt * 16 + quad * 4;
#pragma unroll
            for (int r = 0; r < 4; r++) {
                int row = row0 + r;
                float bs = brep[row];
                f32x4 o4 = {acc[mt][0][r] + bs, acc[mt][1][r] + bs,
                            acc[mt][2][r] + bs, acc[mt][3][r] + bs};
                *(f32x4*)(out + (size_t)(b * CH + row) * SPAT + s0 + 4 * l15) = o4;
            }
        }
    }
}

extern "C" void kernel_launch(void* const* d_in, const int* in_sizes, int n_in,
                              void* d_out, int out_size, void* d_ws, size_t ws_size,
                              hipStream_t stream) {
    (void)in_sizes; (void)n_in; (void)out_size; (void)ws_size;
    const float* x     = (const float*)d_in[0];
    const float* gamma = (const float*)d_in[1];
    const float* beta  = (const float*)d_in[2];
    const float* wk    = (const float*)d_in[3];
    const float* bk    = (const float*)d_in[4];
    const float* wq    = (const float*)d_in[5];
    const float* bq    = (const float*)d_in[6];
    const float* wv    = (const float*)d_in[7];
    const float* bv    = (const float*)d_in[8];
    const float* wfc1  = (const float*)d_in[9];
    const float* bfc1  = (const float*)d_in[10];
    const float* wfc2  = (const float*)d_in[11];
    const float* bfc2  = (const float*)d_in[12];
    const float* wse   = (const float*)d_in[13];
    const float* bse   = (const float*)d_in[14];
    const float* wrep  = (const float*)d_in[15];
    const float* brep  = (const float*)d_in[16];

    float* ws = (float*)d_ws;
    __bf16* wkb = (__bf16*)(ws + WS_WKBF);
    __bf16* wqb = (__bf16*)(ws + WS_WQBF);
    __bf16* wvb = (__bf16*)(ws + WS_WVBF);
    __bf16* Mbf = (__bf16*)(ws + WS_MBF);

    // ctx partials (32 MB) live at the start of d_out; consumed by ea_ctxred
    // before ea_final overwrites d_out with the real output.
    float* ctxpart = (float*)d_out;
    float* out = (float*)d_out;

    hipMemsetAsync((void*)(ws + WS_ROWSUM), 0,
                   (size_t)(WS_CTX - WS_ROWSUM) * sizeof(float), stream);
    ea_bnstats<<<2048, 256, 0, stream>>>(x, ws + WS_SUM, ws + WS_SSUM);
    ea_fold<<<256, 256, 0, stream>>>(wk, wq, wv, bk, bq, bv, gamma, beta,
                                     ws + WS_SUM, ws + WS_SSUM,
                                     wkb, wqb, wvb, ws + WS_BKF, ws + WS_BQF, ws + WS_BVF);
    ea_kvctx<<<256, 512, 0, stream>>>(x, wkb, wvb, ws + WS_BKF, ws + WS_BVF,
                                      ctxpart, ws + WS_ROWSUM);
    ea_ctxred<<<256, 256, 0, stream>>>(ctxpart, ws + WS_ROWSUM, ws + WS_CTX, ws + WS_POOLED);
    ea_M<<<64, 256, 0, stream>>>(ws + WS_CTX, ws + WS_POOLED, wfc1, bfc1, wfc2, bfc2,
                                 wse, bse, wrep, Mbf);
    ea_final<<<2048, 256, 0, stream>>>(x, wqb, ws + WS_BQF, Mbf, brep, out);
}

// Round 4
// 575.784 us; speedup vs baseline: 1.3060x; 1.0310x over previous
//
#include <hip/hip_runtime.h>
#include <hip/hip_bf16.h>

#define BATCH 8
#define CH 256
#define SPAT 16384
#define TP 64       // pixel tile

typedef __attribute__((ext_vector_type(4))) float f32x4;
typedef __attribute__((ext_vector_type(8))) __bf16 bf16x8;
typedef __attribute__((ext_vector_type(4))) __bf16 bf16x4;

// workspace float offsets
#define WS_ROWSUM  512      // 2048  (zeroed)
#define WS_POOLED  2560     // 16   (zeroed)
#define WS_BKF     2576     // 256 folded biases
#define WS_BQF     2832
#define WS_BVF     3088
#define WS_SUM     3344     // 256 (zeroed)
#define WS_SSUM    3600     // 256 (zeroed)
#define WS_CTX     4096     // 16*128*128 = 262144 (written whole by ea_ctxred)
#define WS_MBF     266240   // 8*256*256 bf16 = 262144 floats
#define WS_WKBF    528384   // 65536 bf16 = 32768 floats
#define WS_WQBF    561152
#define WS_WVBF    593920

__device__ __forceinline__ void blockReduce2(float& a, float& b, volatile float* sm) {
    int lane = threadIdx.x & 63, w = threadIdx.x >> 6;
#pragma unroll
    for (int o = 32; o; o >>= 1) { a += __shfl_down(a, o); b += __shfl_down(b, o); }
    if (lane == 0) { sm[w] = a; sm[4 + w] = b; }
    __syncthreads();
    if (threadIdx.x == 0) {
        a = sm[0] + sm[1] + sm[2] + sm[3];
        b = sm[4] + sm[5] + sm[6] + sm[7];
    }
}

// ---- BN batch stats: per-(b,c) partial sums, atomically accumulated ----
__global__ __launch_bounds__(256) void ea_bnstats(const float* __restrict__ x,
                                                  float* sums, float* ssums) {
    __shared__ float sm[8];
    int bi = blockIdx.x, c = bi >> 3, b = bi & 7;
    const float4* p = (const float4*)(x + (size_t)(b * CH + c) * SPAT);
    float sum = 0.f, ss = 0.f;
#pragma unroll 4
    for (int i = threadIdx.x; i < SPAT / 4; i += 256) {
        float4 v = p[i];
        sum += v.x + v.y + v.z + v.w;
        ss  += v.x * v.x + v.y * v.y + v.z * v.z + v.w * v.w;
    }
    blockReduce2(sum, ss, sm);
    if (threadIdx.x == 0) { atomicAdd(sums + c, sum); atomicAdd(ssums + c, ss); }
}

// ---- fold BN scale/shift into bf16 weights + fp32 biases ----
__global__ __launch_bounds__(256) void ea_fold(const float* __restrict__ wk, const float* __restrict__ wq,
        const float* __restrict__ wv, const float* __restrict__ bk, const float* __restrict__ bq,
        const float* __restrict__ bv, const float* __restrict__ gamma, const float* __restrict__ beta,
        const float* __restrict__ sums, const float* __restrict__ ssums,
        __bf16* wkb, __bf16* wqb, __bf16* wvb, float* bkf, float* bqf, float* bvf) {
    __shared__ float sm[12];
    int o = blockIdx.x, c = threadIdx.x;
    const float inv = 1.f / (float)(BATCH * SPAT);
    float mean = sums[c] * inv;
    float var  = ssums[c] * inv - mean * mean;
    float sc   = gamma[c] * rsqrtf(var + 1e-5f);
    float sh   = beta[c] - mean * sc;
    float k = wk[o * 256 + c], q = wq[o * 256 + c], v = wv[o * 256 + c];
    wkb[o * 256 + c] = (__bf16)(k * sc);
    wqb[o * 256 + c] = (__bf16)(q * sc);
    wvb[o * 256 + c] = (__bf16)(v * sc);
    float ak = k * sh, aq = q * sh, av = v * sh;
    int lane = c & 63, w = c >> 6;
#pragma unroll
    for (int off = 32; off; off >>= 1) {
        ak += __shfl_down(ak, off);
        aq += __shfl_down(aq, off);
        av += __shfl_down(av, off);
    }
    if (lane == 0) { sm[w] = ak; sm[4 + w] = aq; sm[8 + w] = av; }
    __syncthreads();
    if (c == 0) {
        bkf[o] = bk[o] + sm[0] + sm[1] + sm[2] + sm[3];
        bqf[o] = bq[o] + sm[4] + sm[5] + sm[6] + sm[7];
        bvf[o] = bv[o] + sm[8] + sm[9] + sm[10] + sm[11];
    }
}

// ---- fused K/V projection + context accumulation ----
// 256 blocks = (batch b, 512-px chunk); 512 threads = 8 waves; 8 tiles of 64 px.
// X LDS: addr = px*256 + (c ^ ((px>>2 & 7)<<3)); staged via PACKED b128 writes
// (bf16x8 along channel) — conflict-free-optimal (8 slots x 8 rows).
__global__ __launch_bounds__(512, 2) void ea_kvctx(const float* __restrict__ x,
        const __bf16* __restrict__ wkb, const __bf16* __restrict__ wvb,
        const float* __restrict__ bkf, const float* __restrict__ bvf,
        float* __restrict__ ctxpart, float* __restrict__ rowsum) {
    __shared__ __bf16 Xl[2 * 64 * 256];   // 64 KB double-buffered x tile
    __shared__ __bf16 Pl[256 * 64];       // 32 KB p = exp(k) tile
    __shared__ __bf16 Vl[256 * 64];       // 32 KB v tile
    const int bi = blockIdx.x, b = bi >> 5, chunk = bi & 31;
    const int t = threadIdx.x;
    const int lane = t & 63, wave = t >> 6, quad = lane >> 4, l15 = lane & 15;
    const int rbase = wave * 32;              // proj output rows for this wave
    const int sl = t & 15, cg = t >> 4;       // staging: px0 = 4*sl, ch = cg*8..+7
    const int xswz = (sl & 7) << 3;
    const float* xp0 = x + (size_t)(b * CH + cg * 8) * SPAT + chunk * 512 + 4 * sl;

    float bkr[2][4], bvr[2][4];
#pragma unroll
    for (int mt = 0; mt < 2; mt++)
#pragma unroll
        for (int r = 0; r < 4; r++) {
            int row = rbase + mt * 16 + quad * 4 + r;
            bkr[mt][r] = bkf[row];
            bvr[mt][r] = bvf[row];
        }

    const f32x4 z = {0.f, 0.f, 0.f, 0.f};
    f32x4 cacc[4][4];
#pragma unroll
    for (int vt = 0; vt < 4; vt++)
#pragma unroll
        for (int kt = 0; kt < 4; kt++) cacc[vt][kt] = z;
    float rs_acc[2][4] = {{0.f, 0.f, 0.f, 0.f}, {0.f, 0.f, 0.f, 0.f}};

    const int head = wave >> 2, rh = (wave >> 1) & 1, chh = wave & 1;
    const int prow0 = head * 128 + rh * 64, vrow0 = head * 128 + chh * 64;

    // prologue: stage tile 0 (pack bf16x8 along channel -> 4 x ds_write_b128)
    f32x4 xr[8];
#pragma unroll
    for (int i = 0; i < 8; i++) xr[i] = *(const f32x4*)(xp0 + (size_t)i * SPAT);
#pragma unroll
    for (int j = 0; j < 4; j++) {
        bf16x8 w;
#pragma unroll
        for (int i = 0; i < 8; i++) w[i] = (__bf16)xr[i][j];
        *(bf16x8*)(Xl + (4 * sl + j) * 256 + ((cg * 8) ^ xswz)) = w;
    }
    __syncthreads();

    int buf = 0;
    for (int tt = 0; tt < 8; tt++) {
        // fused K+V projection: 32 rows x 64 px, K=256; B-frags shared between K and V
        const __bf16* Xb = Xl + buf * (64 * 256);
        f32x4 ak[2][4], av[2][4];
#pragma unroll
        for (int mt = 0; mt < 2; mt++)
#pragma unroll
            for (int nt = 0; nt < 4; nt++) { ak[mt][nt] = z; av[mt][nt] = z; }
#pragma unroll 2
        for (int ks = 0; ks < 8; ks++) {
            int k0 = ks * 32 + quad * 8;
            bf16x8 bb[4];
#pragma unroll
            for (int nt = 0; nt < 4; nt++)
                bb[nt] = *(const bf16x8*)(Xb + (4 * l15 + nt) * 256 + (k0 ^ ((l15 & 7) << 3)));
            bf16x8 aK[2], aV[2];
#pragma unroll
            for (int mt = 0; mt < 2; mt++) {
                size_t off = (size_t)(rbase + mt * 16 + l15) * 256 + k0;
                aK[mt] = *(const bf16x8*)(wkb + off);
                aV[mt] = *(const bf16x8*)(wvb + off);
            }
#pragma unroll
            for (int mt = 0; mt < 2; mt++)
#pragma unroll
                for (int nt = 0; nt < 4; nt++) {
                    ak[mt][nt] = __builtin_amdgcn_mfma_f32_16x16x32_bf16(aK[mt], bb[nt], ak[mt][nt], 0, 0, 0);
                    av[mt][nt] = __builtin_amdgcn_mfma_f32_16x16x32_bf16(aV[mt], bb[nt], av[mt][nt], 0, 0, 0);
                }
        }
        // issue next tile's global loads AFTER proj (weight waits don't drain them)
        if (tt < 7) {
            const float* xp = xp0 + (tt + 1) * 64;
#pragma unroll
            for (int i = 0; i < 8; i++) xr[i] = *(const f32x4*)(xp + (size_t)i * SPAT);
        }
        // epilogue: p = exp(k + bk) -> Pl, v + bv -> Vl, rowsum in regs
#pragma unroll
        for (int mt = 0; mt < 2; mt++)
#pragma unroll
            for (int r = 0; r < 4; r++) {
                int row = rbase + mt * 16 + quad * 4 + r;
                float bK = bkr[mt][r], bV = bvr[mt][r];
                float e0 = __expf(ak[mt][0][r] + bK);
                float e1 = __expf(ak[mt][1][r] + bK);
                float e2 = __expf(ak[mt][2][r] + bK);
                float e3 = __expf(ak[mt][3][r] + bK);
                rs_acc[mt][r] += e0 + e1 + e2 + e3;
                int pa = row * 64 + ((4 * l15) ^ ((row & 7) << 3));
                bf16x4 pk = {(__bf16)e0, (__bf16)e1, (__bf16)e2, (__bf16)e3};
                *(bf16x4*)(Pl + pa) = pk;
                bf16x4 vk = {(__bf16)(av[mt][0][r] + bV), (__bf16)(av[mt][1][r] + bV),
                             (__bf16)(av[mt][2][r] + bV), (__bf16)(av[mt][3][r] + bV)};
                *(bf16x4*)(Vl + pa) = vk;
            }
        __syncthreads();
        // ctx quadrant, SWAPPED operands: cacc[vt][kt] rows=vv, cols=kk
#pragma unroll
        for (int ks = 0; ks < 2; ks++) {
            int k0 = ks * 32 + quad * 8;
            bf16x8 pfr[4], vfr[4];
#pragma unroll
            for (int kt = 0; kt < 4; kt++) {
                int row = prow0 + kt * 16 + l15;
                pfr[kt] = *(const bf16x8*)(Pl + row * 64 + (k0 ^ ((row & 7) << 3)));
            }
#pragma unroll
            for (int vt = 0; vt < 4; vt++) {
                int row = vrow0 + vt * 16 + l15;
                vfr[vt] = *(const bf16x8*)(Vl + row * 64 + (k0 ^ ((row & 7) << 3)));
            }
#pragma unroll
            for (int vt = 0; vt < 4; vt++)
#pragma unroll
                for (int kt = 0; kt < 4; kt++)
                    cacc[vt][kt] = __builtin_amdgcn_mfma_f32_16x16x32_bf16(vfr[vt], pfr[kt], cacc[vt][kt], 0, 0, 0);
        }
        // write next X tile (regs -> LDS, packed b128) after ctx reads
        if (tt < 7) {
            __bf16* Xn = Xl + (buf ^ 1) * (64 * 256);
#pragma unroll
            for (int j = 0; j < 4; j++) {
                bf16x8 w;
#pragma unroll
                for (int i = 0; i < 8; i++) w[i] = (__bf16)xr[i][j];
                *(bf16x8*)(Xn + (4 * sl + j) * 256 + ((cg * 8) ^ xswz)) = w;
            }
        }
        __syncthreads();
        buf ^= 1;
    }
    // flush rowsum: reduce over the 16 px-lanes, one atomic per row
#pragma unroll
    for (int mt = 0; mt < 2; mt++)
#pragma unroll
        for (int r = 0; r < 4; r++) {
            float v = rs_acc[mt][r];
            v += __shfl_xor(v, 1);
            v += __shfl_xor(v, 2);
            v += __shfl_xor(v, 4);
            v += __shfl_xor(v, 8);
            if (l15 == 0)
                atomicAdd(rowsum + b * CH + rbase + mt * 16 + quad * 4 + r, v);
        }
    // flush ctx partials: PLAIN coalesced stores to private slice [kk][vv]
    float* pbase = ctxpart + (((size_t)(b * 32 + chunk)) * 2 + head) * 16384;
#pragma unroll
    for (int vt = 0; vt < 4; vt++)
#pragma unroll
        for (int kt = 0; kt < 4; kt++) {
            int kk = rh * 64 + kt * 16 + l15;
            int vv = chh * 64 + vt * 16 + quad * 4;
            *(f32x4*)(pbase + kk * 128 + vv) = cacc[vt][kt];
        }
}

// ---- reduce ctx partials over 32 chunks, normalize by rowsum, pooled partial ----
__global__ __launch_bounds__(256) void ea_ctxred(const float* __restrict__ part,
        const float* __restrict__ rowsum, float* __restrict__ ctx, float* __restrict__ pooled) {
    __shared__ float sm[8];
    int bi = blockIdx.x, b = bi >> 5, h = (bi >> 4) & 1, ks = bi & 15;
    int t = threadIdx.x;
    int kk = ks * 8 + (t >> 5), vv = (t & 31) * 4;
    const float* p0 = part + (((size_t)b * 32) * 2 + h) * 16384 + (size_t)kk * 128 + vv;
    f32x4 acc = {0.f, 0.f, 0.f, 0.f};
#pragma unroll 4
    for (int c = 0; c < 32; c++) {
        f32x4 v = *(const f32x4*)(p0 + (size_t)c * 32768);
        acc[0] += v[0]; acc[1] += v[1]; acc[2] += v[2]; acc[3] += v[3];
    }
    float inv = 1.f / rowsum[b * CH + h * 128 + kk];
    f32x4 o = {acc[0] * inv, acc[1] * inv, acc[2] * inv, acc[3] * inv};
    *(f32x4*)(ctx + ((size_t)b * 2 + h) * 16384 + (size_t)kk * 128 + vv) = o;
    float s = o[0] + o[1] + o[2] + o[3], d = 0.f;
    blockReduce2(s, d, sm);
    if (t == 0) atomicAdd(pooled + b * 2 + h, s);
}

// ---- SE gate + fold w_rep ----
__global__ __launch_bounds__(256) void ea_M(const float* ctx, const float* pooled,
                                            const float* wfc1, const float* bfc1,
                                            const float* wfc2, const float* bfc2,
                                            const float* wse, const float* bse,
                                            const float* wrep, __bf16* Mbf) {
    __shared__ float L[128 * 128];
    int bi = blockIdx.x, b = bi >> 3, h = (bi >> 2) & 1, strip = bi & 3;
    float p0 = pooled[b * 2] * (1.f / 16384.f), p1 = pooled[b * 2 + 1] * (1.f / 16384.f);
    float z10 = fmaxf(0.f, wfc1[0] * p0 + wfc1[1] * p1 + bfc1[0]);
    float z11 = fmaxf(0.f, wfc1[2] * p0 + wfc1[3] * p1 + bfc1[1]);
    float z20 = wfc2[0] * z10 + wfc2[1] * z11 + bfc2[0];
    float z21 = wfc2[2] * z10 + wfc2[3] * z11 + bfc2[1];
    float g0 = 1.f / (1.f + __expf(-z20)), g1 = 1.f / (1.f + __expf(-z21));
    float a0 = wse[0] * g0, a1 = wse[1] * g1, bs = bse[0];
    const float* c0 = ctx + (size_t)b * 2 * 16384;
    const float* c1 = c0 + 16384;
    for (int i = threadIdx.x; i < 16384; i += 256) L[i] = a0 * c0[i] + a1 * c1[i] + bs;
    __syncthreads();
    int o = strip * 64 + (threadIdx.x & 63), kb = (threadIdx.x >> 6) * 32;
    const float4* wr = (const float4*)(wrep + (size_t)o * 256 + h * 128);
    for (int kk = kb; kk < kb + 32; kk++) {
        const float4* Lr = (const float4*)(L + kk * 128);
        float acc = 0.f;
#pragma unroll 8
        for (int j = 0; j < 32; j++) {
            float4 w4 = wr[j];
            float4 l4 = Lr[j];
            acc += w4.x * l4.x + w4.y * l4.y + w4.z * l4.z + w4.w * l4.w;
        }
        Mbf[(size_t)(b * 256 + o) * 256 + h * 128 + kk] = (__bf16)acc;
    }
}

// per-wave 64x64 strip of a [256 x 64px] GEMM, K=256 (ea_final)
// B in LDS [px][256], swizzle c ^ ((px>>2 & 7)<<3)
__device__ __forceinline__ void mm256(const __bf16* __restrict__ A, const __bf16* Xl,
                                      int WB, int quad, int l15, f32x4 (&acc)[4][4]) {
#pragma unroll 2
    for (int ks = 0; ks < 8; ks++) {
        int k0 = ks * 32 + quad * 8;
        bf16x8 a[4];
#pragma unroll
        for (int mt = 0; mt < 4; mt++)
            a[mt] = *(const bf16x8*)(A + (WB + mt * 16 + l15) * 256 + k0);
        bf16x8 bb[4];
#pragma unroll
        for (int nt = 0; nt < 4; nt++)
            bb[nt] = *(const bf16x8*)(Xl + (4 * l15 + nt) * 256 + (k0 ^ ((l15 & 7) << 3)));
#pragma unroll
        for (int mt = 0; mt < 4; mt++)
#pragma unroll
            for (int nt = 0; nt < 4; nt++)
                acc[mt][nt] = __builtin_amdgcn_mfma_f32_16x16x32_bf16(a[mt], bb[nt], acc[mt][nt], 0, 0, 0);
    }
}

// ---- final: q = wq'@x+bq', channel-softmax per head, out = M@qsoft + b_rep ----
// Single LDS buffer XQ reused for X then Q (extra barrier); packed b128 staging.
__global__ __launch_bounds__(256, 3) void ea_final(const float* __restrict__ x,
        const __bf16* __restrict__ wqb, const float* __restrict__ bqf,
        const __bf16* __restrict__ Mbf, const float* __restrict__ brep, float* __restrict__ out) {
    __shared__ __bf16 XQ[TP * 256];   // 32 KB, X then Q
    __shared__ float psum[256];
    __shared__ float rcp[TP * 2];
    int bi = blockIdx.x, b = bi >> 8, s0 = (bi & 255) * TP, t = threadIdx.x;

    // stage x tile: threads (sl px-group, cg 16-ch group); two 8-ch halves to cap VGPR
    {
        int sl = t & 15, cg = t >> 4;
        int xswz = (sl & 7) << 3;
        const float* xp = x + (size_t)(b * CH + cg * 16) * SPAT + s0 + 4 * sl;
#pragma unroll
        for (int half = 0; half < 2; half++) {
            f32x4 xr[8];
#pragma unroll
            for (int i = 0; i < 8; i++)
                xr[i] = *(const f32x4*)(xp + (size_t)(half * 8 + i) * SPAT);
#pragma unroll
            for (int j = 0; j < 4; j++) {
                bf16x8 w;
#pragma unroll
                for (int i = 0; i < 8; i++) w[i] = (__bf16)xr[i][j];
                *(bf16x8*)(XQ + (4 * sl + j) * 256 + ((cg * 16 + half * 8) ^ xswz)) = w;
            }
        }
    }
    __syncthreads();

    int lane = t & 63, wave = t >> 6, quad = lane >> 4, l15 = lane & 15, WB = wave * 64;
    const f32x4 z = {0.f, 0.f, 0.f, 0.f};

    // matmul1: q-logits (X fully read into acc before Q overwrites the buffer)
    f32x4 acc[4][4];
#pragma unroll
    for (int mt = 0; mt < 4; mt++)
#pragma unroll
        for (int nt = 0; nt < 4; nt++) acc[mt][nt] = z;
    mm256(wqb, XQ, WB, quad, l15, acc);
    __syncthreads();   // all waves done reading X

    // epilogue: exp -> Q into the same buffer
#pragma unroll
    for (int mt = 0; mt < 4; mt++) {
        int row0 = WB + mt * 16 + quad * 4;
#pragma unroll
        for (int nt = 0; nt < 4; nt++) {
            int px = 4 * l15 + nt;
            bf16x4 qk;
#pragma unroll
            for (int r = 0; r < 4; r++)
                qk[r] = (__bf16)__expf(acc[mt][nt][r] + bqf[row0 + r]);
            *(bf16x4*)(XQ + px * 256 + (row0 ^ ((l15 & 7) << 3))) = qk;
        }
    }
    __syncthreads();
    // column sums per (px, head)
    {
        int px = t & 63, hh = (t >> 6) & 1, part = t >> 7;
        int cb = hh * 128 + part * 64;
        int swz = ((px >> 2) & 7) << 3;
        float s = 0.f;
#pragma unroll
        for (int j = 0; j < 8; j++) {
            bf16x8 qv = *(const bf16x8*)(XQ + px * 256 + ((cb + j * 8) ^ swz));
#pragma unroll
            for (int e = 0; e < 8; e++) s += (float)qv[e];
        }
        psum[t] = s;
    }
    __syncthreads();
    if (t < 128) {
        float tot = psum[t] + psum[t + 128];
        rcp[(t & 63) * 2 + (t >> 6)] = 1.f / tot;
    }
    __syncthreads();
    // normalize Q in place
#pragma unroll 2
    for (int e = t; e < TP * 32; e += 256) {
        int px = e >> 5, cc = (e & 31) * 8;
        float sc = rcp[px * 2 + (cc >> 7)];
        int h = px * 256 + (cc ^ (((px >> 2) & 7) << 3));
        bf16x8 qv = *(const bf16x8*)(XQ + h);
        bf16x8 qo;
#pragma unroll
        for (int j2 = 0; j2 < 8; j2++) qo[j2] = (__bf16)((float)qv[j2] * sc);
        *(bf16x8*)(XQ + h) = qo;
    }
    __syncthreads();
    // matmul2: out = M @ qsoft + b_rep
#pragma unroll
    for (int mt = 0; mt < 4; mt++)
#pragma unroll
        for (int nt = 0; nt < 4; nt++) acc[mt][nt] = z;
    mm256(Mbf + (size_t)b * 65536, XQ, WB, quad, l15, acc);
#pragma unroll
    for (int mt = 0; mt < 4; mt++) {
        int row0 = WB + mt * 16 + quad * 4;
#pragma unroll
        for (int r = 0; r < 4; r++) {
            int row = row0 + r;
            float bs = brep[row];
            f32x4 o4 = {acc[mt][0][r] + bs, acc[mt][1][r] + bs,
                        acc[mt][2][r] + bs, acc[mt][3][r] + bs};
            *(f32x4*)(out + (size_t)(b * CH + row) * SPAT + s0 + 4 * l15) = o4;
        }
    }
}

extern "C" void kernel_launch(void* const* d_in, const int* in_sizes, int n_in,
                              void* d_out, int out_size, void* d_ws, size_t ws_size,
                              hipStream_t stream) {
    (void)in_sizes; (void)n_in; (void)out_size; (void)ws_size;
    const float* x     = (const float*)d_in[0];
    const float* gamma = (const float*)d_in[1];
    const float* beta  = (const float*)d_in[2];
    const float* wk    = (const float*)d_in[3];
    const float* bk    = (const float*)d_in[4];
    const float* wq    = (const float*)d_in[5];
    const float* bq    = (const float*)d_in[6];
    const float* wv    = (const float*)d_in[7];
    const float* bv    = (const float*)d_in[8];
    const float* wfc1  = (const float*)d_in[9];
    const float* bfc1  = (const float*)d_in[10];
    const float* wfc2  = (const float*)d_in[11];
    const float* bfc2  = (const float*)d_in[12];
    const float* wse   = (const float*)d_in[13];
    const float* bse   = (const float*)d_in[14];
    const float* wrep  = (const float*)d_in[15];
    const float* brep  = (const float*)d_in[16];

    float* ws = (float*)d_ws;
    __bf16* wkb = (__bf16*)(ws + WS_WKBF);
    __bf16* wqb = (__bf16*)(ws + WS_WQBF);
    __bf16* wvb = (__bf16*)(ws + WS_WVBF);
    __bf16* Mbf = (__bf16*)(ws + WS_MBF);

    // ctx partials (32 MB) live at the start of d_out; consumed by ea_ctxred
    // before ea_final overwrites d_out with the real output.
    float* ctxpart = (float*)d_out;
    float* out = (float*)d_out;

    hipMemsetAsync((void*)(ws + WS_ROWSUM), 0,
                   (size_t)(WS_CTX - WS_ROWSUM) * sizeof(float), stream);
    ea_bnstats<<<2048, 256, 0, stream>>>(x, ws + WS_SUM, ws + WS_SSUM);
    ea_fold<<<256, 256, 0, stream>>>(wk, wq, wv, bk, bq, bv, gamma, beta,
                                     ws + WS_SUM, ws + WS_SSUM,
                                     wkb, wqb, wvb, ws + WS_BKF, ws + WS_BQF, ws + WS_BVF);
    ea_kvctx<<<256, 512, 0, stream>>>(x, wkb, wvb, ws + WS_BKF, ws + WS_BVF,
                                      ctxpart, ws + WS_ROWSUM);
    ea_ctxred<<<256, 256, 0, stream>>>(ctxpart, ws + WS_ROWSUM, ws + WS_CTX, ws + WS_POOLED);
    ea_M<<<64, 256, 0, stream>>>(ws + WS_CTX, ws + WS_POOLED, wfc1, bfc1, wfc2, bfc2,
                                 wse, bse, wrep, Mbf);
    ea_final<<<2048, 256, 0, stream>>>(x, wqb, ws + WS_BQF, Mbf, brep, out);
}